// Round 4
// baseline (496.827 us; speedup 1.0000x reference)
//
#include <hip/hip_runtime.h>
#include <hip/hip_cooperative_groups.h>
#include <math.h>

namespace cg = cooperative_groups;

// Problem constants (fixed by setup_inputs): B=16, T=4096, D=512, fp32.
#define BB 16
#define TT 4096
#define DD 512
#define D4 128              // DD / 4 (float4 columns)

// Fused (cooperative) decomposition: 128 chunks x 32 steps.
constexpr int CCF = 128;
constexpr int LLF = TT / CCF;   // 32
// Fallback (3-kernel) decomposition: 256 chunks x 16 steps.
constexpr int CC  = 256;
constexpr int LL  = TT / CC;    // 16

typedef float floatx4 __attribute__((ext_vector_type(4)));

__device__ __forceinline__ float sigmf(float v) {
    return 1.0f / (1.0f + expf(-v));
}

// ===========================================================================
// Fused single-launch cooperative kernel.
// Grid: 1024 blocks x 256 thr (4 blocks/CU co-resident via launch_bounds).
// Block (cx, ) handles chunk c = cx & 127 for b-pair bp = cx >> 7;
// thread = (b within pair) x (d4 column).
// ===========================================================================
__global__ __launch_bounds__(256, 4) void es_fused(
    const float* __restrict__ x, const float* __restrict__ alpha,
    float* __restrict__ ends, float* __restrict__ out)
{
    const int tid = threadIdx.x;
    const int c   = blockIdx.x & (CCF - 1);
    const int b   = ((blockIdx.x >> 7) << 1) + (tid >> 7);
    const int d4  = tid & 127;

    const float4 al = reinterpret_cast<const float4*>(alpha)[d4];
    const float ax = sigmf(al.x), ay = sigmf(al.y), az = sigmf(al.z), aw = sigmf(al.w);
    const float fx = 1.0f - ax, fy = 1.0f - ay, fz = 1.0f - az, fw = 1.0f - aw;

    const size_t base = ((size_t)b * TT + (size_t)c * LLF) * D4 + d4;

    // ---- Phase 1: local chunk scan (zero init; chunk 0 exact), publish end.
    {
        const float4* xp = reinterpret_cast<const float4*>(x) + base;
        constexpr int W = 8;              // rolling load window (MLP)
        float4 w[W];
        #pragma unroll
        for (int j = 0; j < W; ++j) w[j] = xp[(size_t)j * D4];

        float4 s;
        if (c == 0) s = w[0];             // virtual s_{-1} = x_0
        else        { s.x = s.y = s.z = s.w = 0.0f; }

        #pragma unroll
        for (int i = 0; i < LLF; ++i) {
            const float4 v = w[i & (W - 1)];
            if (i + W < LLF) w[i & (W - 1)] = xp[(size_t)(i + W) * D4];
            s.x = fmaf(ax, v.x, fx * s.x);
            s.y = fmaf(ay, v.y, fy * s.y);
            s.z = fmaf(az, v.z, fz * s.z);
            s.w = fmaf(aw, v.w, fw * s.w);
        }
        reinterpret_cast<float4*>(ends)[((size_t)b * CCF + c) * D4 + d4] = s;
    }

    cg::this_grid().sync();

    // ---- Phase 2: carry scan across chunks, done by 2048 threads (blocks 0..7).
    {
        const int g = blockIdx.x * 256 + tid;
        if (g < BB * D4) {
            const int sb  = g >> 7;
            const int sd4 = g & 127;
            const float4 sal = reinterpret_cast<const float4*>(alpha)[sd4];
            float4 fL;
            fL.x = powf(1.0f - sigmf(sal.x), (float)LLF);
            fL.y = powf(1.0f - sigmf(sal.y), (float)LLF);
            fL.z = powf(1.0f - sigmf(sal.z), (float)LLF);
            fL.w = powf(1.0f - sigmf(sal.w), (float)LLF);

            float4* e = reinterpret_cast<float4*>(ends) + (size_t)sb * CCF * D4 + sd4;

            constexpr int P = 8;
            float4 buf[P];
            #pragma unroll
            for (int j = 0; j < P; ++j) buf[j] = e[(size_t)(1 + j) * D4];

            float4 S = e[0];              // S_0 = E_0 (exact)
            int cc = 1;
            while (cc + P <= CCF) {
                #pragma unroll
                for (int j = 0; j < P; ++j) {
                    const float4 v = buf[j];
                    const int pf = cc + P;
                    if (pf < CCF) buf[j] = e[(size_t)pf * D4];
                    S.x = fmaf(fL.x, S.x, v.x);
                    S.y = fmaf(fL.y, S.y, v.y);
                    S.z = fmaf(fL.z, S.z, v.z);
                    S.w = fmaf(fL.w, S.w, v.w);
                    e[(size_t)cc * D4] = S;
                    ++cc;
                }
            }
            for (int j = 0; cc < CCF; ++cc, ++j) {
                const float4 v = buf[j];
                S.x = fmaf(fL.x, S.x, v.x);
                S.y = fmaf(fL.y, S.y, v.y);
                S.z = fmaf(fL.z, S.z, v.z);
                S.w = fmaf(fL.w, S.w, v.w);
                e[(size_t)cc * D4] = S;
            }
        }
    }

    cg::this_grid().sync();

    // ---- Phase 3: reload x (L3-hot), start from exact carry, NT-store out.
    {
        const float4* xp = reinterpret_cast<const float4*>(x) + base;
        // Launder the pointer so the compiler cannot CSE phase-1 loads across
        // the grid sync (would hold 32 float4 live -> spill).
        asm volatile("" : "+v"(xp));
        floatx4* op = reinterpret_cast<floatx4*>(out) + base;

        float4 s;
        if (c != 0) {   // wave-uniform (c per-block)
            s = reinterpret_cast<const float4*>(ends)[((size_t)b * CCF + (c - 1)) * D4 + d4];
        }

        constexpr int W = 8;
        float4 w[W];
        #pragma unroll
        for (int j = 0; j < W; ++j) w[j] = xp[(size_t)j * D4];
        if (c == 0) s = w[0];             // s_{-1} = x_0

        #pragma unroll
        for (int i = 0; i < LLF; ++i) {
            const float4 v = w[i & (W - 1)];
            if (i + W < LLF) w[i & (W - 1)] = xp[(size_t)(i + W) * D4];
            s.x = fmaf(ax, v.x, fx * s.x);
            s.y = fmaf(ay, v.y, fy * s.y);
            s.z = fmaf(az, v.z, fz * s.z);
            s.w = fmaf(aw, v.w, fw * s.w);
            floatx4 sv = { s.x, s.y, s.z, s.w };
            __builtin_nontemporal_store(sv, op + (size_t)i * D4);
        }
    }
}

// ===========================================================================
// Fallback 3-kernel path (used if cooperative launch unsupported or ws small).
// ===========================================================================
__global__ __launch_bounds__(256) void es_chunk_ends(
    const float* __restrict__ x, const float* __restrict__ alpha,
    float* __restrict__ ends)
{
    const int c   = blockIdx.x;
    const int tid = threadIdx.x;
    const int b   = (blockIdx.y << 1) + (tid >> 7);
    const int d4  = tid & 127;

    const float4* xp = reinterpret_cast<const float4*>(x)
                     + ((size_t)b * TT + (size_t)c * LL) * D4 + d4;

    float4 v[LL];
    #pragma unroll
    for (int i = 0; i < LL; ++i) v[i] = xp[(size_t)i * D4];

    const float4 al = reinterpret_cast<const float4*>(alpha)[d4];
    const float ax = sigmf(al.x), ay = sigmf(al.y), az = sigmf(al.z), aw = sigmf(al.w);
    const float fx = 1.0f - ax, fy = 1.0f - ay, fz = 1.0f - az, fw = 1.0f - aw;

    float4 s;
    if (c == 0) s = v[0];
    else        { s.x = s.y = s.z = s.w = 0.0f; }

    #pragma unroll
    for (int i = 0; i < LL; ++i) {
        s.x = fmaf(ax, v[i].x, fx * s.x);
        s.y = fmaf(ay, v[i].y, fy * s.y);
        s.z = fmaf(az, v[i].z, fz * s.z);
        s.w = fmaf(aw, v[i].w, fw * s.w);
    }
    reinterpret_cast<float4*>(ends)[((size_t)b * CC + c) * D4 + d4] = s;
}

__global__ __launch_bounds__(256) void es_carry_scan(
    float* __restrict__ ends, const float* __restrict__ alpha)
{
    const int g  = blockIdx.x * 256 + threadIdx.x;
    const int b  = g >> 7;
    const int d4 = g & 127;

    const float4 al = reinterpret_cast<const float4*>(alpha)[d4];
    float4 fL;
    fL.x = powf(1.0f - sigmf(al.x), (float)LL);
    fL.y = powf(1.0f - sigmf(al.y), (float)LL);
    fL.z = powf(1.0f - sigmf(al.z), (float)LL);
    fL.w = powf(1.0f - sigmf(al.w), (float)LL);

    float4* e = reinterpret_cast<float4*>(ends) + (size_t)b * CC * D4 + d4;

    constexpr int P = 16;
    float4 buf[P];
    #pragma unroll
    for (int j = 0; j < P; ++j) buf[j] = e[(size_t)(1 + j) * D4];

    float4 S = e[0];
    int c = 1;
    while (c + P <= CC) {
        #pragma unroll
        for (int j = 0; j < P; ++j) {
            const float4 v = buf[j];
            const int pf = c + P;
            if (pf < CC) buf[j] = e[(size_t)pf * D4];
            S.x = fmaf(fL.x, S.x, v.x);
            S.y = fmaf(fL.y, S.y, v.y);
            S.z = fmaf(fL.z, S.z, v.z);
            S.w = fmaf(fL.w, S.w, v.w);
            e[(size_t)c * D4] = S;
            ++c;
        }
    }
    for (int j = 0; c < CC; ++c, ++j) {
        const float4 v = buf[j];
        S.x = fmaf(fL.x, S.x, v.x);
        S.y = fmaf(fL.y, S.y, v.y);
        S.z = fmaf(fL.z, S.z, v.z);
        S.w = fmaf(fL.w, S.w, v.w);
        e[(size_t)c * D4] = S;
    }
}

__global__ __launch_bounds__(256) void es_final(
    const float* __restrict__ x, const float* __restrict__ alpha,
    const float* __restrict__ carries, float* __restrict__ out)
{
    const int c   = blockIdx.x;
    const int tid = threadIdx.x;
    const int b   = (blockIdx.y << 1) + (tid >> 7);
    const int d4  = tid & 127;

    float4 s;
    if (c != 0) {
        s = reinterpret_cast<const float4*>(carries)[((size_t)b * CC + (c - 1)) * D4 + d4];
    }

    const size_t base = ((size_t)b * TT + (size_t)c * LL) * D4 + d4;
    const float4* xp = reinterpret_cast<const float4*>(x) + base;
    floatx4*      op = reinterpret_cast<floatx4*>(out) + base;

    float4 v[LL];
    #pragma unroll
    for (int i = 0; i < LL; ++i) v[i] = xp[(size_t)i * D4];

    const float4 al = reinterpret_cast<const float4*>(alpha)[d4];
    const float ax = sigmf(al.x), ay = sigmf(al.y), az = sigmf(al.z), aw = sigmf(al.w);
    const float fx = 1.0f - ax, fy = 1.0f - ay, fz = 1.0f - az, fw = 1.0f - aw;

    if (c == 0) s = v[0];

    #pragma unroll
    for (int i = 0; i < LL; ++i) {
        s.x = fmaf(ax, v[i].x, fx * s.x);
        s.y = fmaf(ay, v[i].y, fy * s.y);
        s.z = fmaf(az, v[i].z, fz * s.z);
        s.w = fmaf(aw, v[i].w, fw * s.w);
        floatx4 sv = { s.x, s.y, s.z, s.w };
        __builtin_nontemporal_store(sv, op + (size_t)i * D4);
    }
}

__global__ __launch_bounds__(256) void es_serial(
    const float* __restrict__ x, const float* __restrict__ alpha,
    float* __restrict__ out)
{
    const int g  = blockIdx.x * 256 + threadIdx.x;
    const int b  = g >> 7;
    const int d4 = g & 127;

    const float4 al = reinterpret_cast<const float4*>(alpha)[d4];
    const float ax = sigmf(al.x), ay = sigmf(al.y), az = sigmf(al.z), aw = sigmf(al.w);
    const float fx = 1.0f - ax, fy = 1.0f - ay, fz = 1.0f - az, fw = 1.0f - aw;

    const float4* xp = reinterpret_cast<const float4*>(x) + (size_t)b * TT * D4 + d4;
    float4*       op = reinterpret_cast<float4*>(out) + (size_t)b * TT * D4 + d4;

    float4 s = xp[0];
    #pragma unroll 4
    for (int t = 0; t < TT; ++t) {
        const float4 v = xp[(size_t)t * D4];
        s.x = fmaf(ax, v.x, fx * s.x);
        s.y = fmaf(ay, v.y, fy * s.y);
        s.z = fmaf(az, v.z, fz * s.z);
        s.w = fmaf(aw, v.w, fw * s.w);
        op[(size_t)t * D4] = s;
    }
}

extern "C" void kernel_launch(void* const* d_in, const int* in_sizes, int n_in,
                              void* d_out, int out_size, void* d_ws, size_t ws_size,
                              hipStream_t stream)
{
    const float* x     = (const float*)d_in[0];
    const float* alpha = (const float*)d_in[1];
    float*       out   = (float*)d_out;

    // Cooperative-launch support (host-side attribute query; deterministic).
    int coop = 0;
    hipDeviceGetAttribute(&coop, hipDeviceAttributeCooperativeLaunch, 0);

    const size_t need_f = (size_t)BB * CCF * DD * sizeof(float);  // 4 MiB
    if (coop && ws_size >= need_f) {
        float* ends = (float*)d_ws;
        void* args[] = { (void*)&x, (void*)&alpha, (void*)&ends, (void*)&out };
        hipError_t err = hipLaunchCooperativeKernel(
            (const void*)es_fused, dim3(BB / 2 * CCF), dim3(256), args, 0, stream);
        if (err == hipSuccess) return;
    }

    const size_t need = (size_t)BB * CC * DD * sizeof(float);     // 8 MiB
    if (ws_size < need) {
        es_serial<<<dim3(8), 256, 0, stream>>>(x, alpha, out);
        return;
    }
    float* ends = (float*)d_ws;
    es_chunk_ends<<<dim3(CC, BB / 2), 256, 0, stream>>>(x, alpha, ends);
    es_carry_scan<<<dim3(8), 256, 0, stream>>>(ends, alpha);
    es_final<<<dim3(CC, BB / 2), 256, 0, stream>>>(x, alpha, ends, out);
}